// Round 1
// baseline (110.267 us; speedup 1.0000x reference)
//
#include <hip/hip_runtime.h>

#define B_ 32
#define N_ 1024
#define NEG 0.01f
#define QSC (1.4426950408889634f/32.0f)   // log2(e)/E folded into staged Wq/bq

using half8  = __attribute__((ext_vector_type(8))) _Float16;
using half4  = __attribute__((ext_vector_type(4))) _Float16;
using half2  = __attribute__((ext_vector_type(2))) _Float16;
using fp16x2 = __attribute__((ext_vector_type(2))) __fp16;
using floatx4 = __attribute__((ext_vector_type(4))) float;

#if defined(__has_builtin)
#if __has_builtin(__builtin_amdgcn_exp2f)
#define EXP2(x) __builtin_amdgcn_exp2f(x)
#endif
#endif
#ifndef EXP2
#define EXP2(x) exp2f(x)
#endif

#define MFMA32 __builtin_amdgcn_mfma_f32_16x16x32_f16
#define MFMA16 __builtin_amdgcn_mfma_f32_16x16x16f16

__device__ inline half2 pkcvt(float a, float b) {
    fp16x2 r = __builtin_amdgcn_cvt_pkrtz(a, b);
    return __builtin_bit_cast(half2, r);
}

__device__ inline half8 cvt8(float4 a, float4 b) {
    half2 p0 = pkcvt(a.x, a.y);
    half2 p1 = pkcvt(a.z, a.w);
    half2 p2 = pkcvt(b.x, b.y);
    half2 p3 = pkcvt(b.z, b.w);
    half8 h = { p0[0],p0[1], p1[0],p1[1], p2[0],p2[1], p3[0],p3[1] };
    return h;
}

// async global->LDS: per-lane gptr, wave-uniform lptr; HW writes lptr + lane*16
__device__ __forceinline__ void gload16(const _Float16* g, _Float16* l) {
#if defined(__has_builtin) && __has_builtin(__builtin_amdgcn_global_load_lds)
    __builtin_amdgcn_global_load_lds(
        (const __attribute__((address_space(1))) unsigned int*)g,
        (__attribute__((address_space(3))) unsigned int*)l, 16, 0, 0);
#else
    int lane = threadIdx.x & 63;
    *(half8*)(l + lane*8) = *(const half8*)g;
#endif
}

// ============================ Kernel P: QKV projection =====================
// 512 blocks = bg(64) x qtile(8 of 128 rows), 256 threads (4 waves x 32 rows).
// Writes f16: Qs[bg][n][e] (pre-scaled, bias folded), Kg[bg][n][e],
// Vg[bg][n][e], Vtg[bg][e][n].
__global__ __launch_bounds__(256, 2) void proj_kernel(
    const float* __restrict__ x, const float* __restrict__ w_qkv, const float* __restrict__ b_qkv,
    _Float16* __restrict__ Qs, _Float16* __restrict__ Kg,
    _Float16* __restrict__ Vg, _Float16* __restrict__ Vtg)
{
    __shared__ struct __align__(16) {
        _Float16 wsh[96*36];
        float    bsh[96];
        _Float16 qk[128*72];     // [row][ Q:0-31 | K:32-63 | pad ]  (stride 72 -> 144B, 16B aligned)
        _Float16 vrow[128*32];   // [row][e]
        _Float16 vt[32*136];     // [e][row]  (stride 136 -> 272B, 16B aligned)
    } sm;
    int t = threadIdx.x;
    int bg = blockIdx.x >> 3;
    int qt = blockIdx.x & 7;
    int b = bg >> 1, g = bg & 1;
    int lane = t & 63, w = t >> 6;
    int L15 = lane & 15, quad = lane >> 4;

    for (int idx = t; idx < 96*32; idx += 256) {
        int r = idx >> 5, c = idx & 31;
        float wv = w_qkv[(g*96 + r)*32 + c];
        sm.wsh[r*36 + c] = (_Float16)(r < 32 ? wv*QSC : wv);
    }
    if (t < 96) sm.bsh[t] = b_qkv[g*96 + t];
    __syncthreads();

    half8 bwq[2], bwk[2], bwv[2];
    floatx4 cq[2], ck[2], cv[2];
    #pragma unroll
    for (int et = 0; et < 2; et++) {
        bwq[et] = *(const half8*)&sm.wsh[(     et*16 + L15)*36 + quad*8];
        bwk[et] = *(const half8*)&sm.wsh[(32 + et*16 + L15)*36 + quad*8];
        bwv[et] = *(const half8*)&sm.wsh[(64 + et*16 + L15)*36 + quad*8];
        float bq = sm.bsh[     et*16 + L15] * QSC;
        float bk = sm.bsh[32 + et*16 + L15];
        float bv = sm.bsh[64 + et*16 + L15];
        cq[et] = (floatx4){bq,bq,bq,bq};
        ck[et] = (floatx4){bk,bk,bk,bk};
        cv[et] = (floatx4){bv,bv,bv,bv};
    }

    #pragma unroll
    for (int mt = 0; mt < 2; mt++) {
        const float* p = x + ((size_t)b*N_ + qt*128 + w*32 + mt*16 + L15)*64 + g*32 + quad*8;
        half8 ax = cvt8(*(const float4*)p, *(const float4*)(p + 4));
        floatx4 dQ[2], dK[2], dV[2];
        #pragma unroll
        for (int et = 0; et < 2; et++) {
            dQ[et] = MFMA32(ax, bwq[et], cq[et], 0,0,0);
            dK[et] = MFMA32(ax, bwk[et], ck[et], 0,0,0);
            dV[et] = MFMA32(ax, bwv[et], cv[et], 0,0,0);
        }
        int rb = w*32 + mt*16 + quad*4;
        #pragma unroll
        for (int et = 0; et < 2; et++) {
            #pragma unroll
            for (int r = 0; r < 4; r++)
                sm.qk[(rb+r)*72 + et*16 + L15] = (_Float16)dQ[et][r];
            half2 k01 = pkcvt(dK[et][0], dK[et][1]);
            half2 k23 = pkcvt(dK[et][2], dK[et][3]);
            sm.qk[(rb+0)*72 + 32 + et*16 + L15] = k01[0];
            sm.qk[(rb+1)*72 + 32 + et*16 + L15] = k01[1];
            sm.qk[(rb+2)*72 + 32 + et*16 + L15] = k23[0];
            sm.qk[(rb+3)*72 + 32 + et*16 + L15] = k23[1];
            half2 v01 = pkcvt(dV[et][0], dV[et][1]);
            half2 v23 = pkcvt(dV[et][2], dV[et][3]);
            half4 vh = { v01[0], v01[1], v23[0], v23[1] };
            sm.vrow[(rb+0)*32 + et*16 + L15] = vh[0];
            sm.vrow[(rb+1)*32 + et*16 + L15] = vh[1];
            sm.vrow[(rb+2)*32 + et*16 + L15] = vh[2];
            sm.vrow[(rb+3)*32 + et*16 + L15] = vh[3];
            *(half4*)&sm.vt[(et*16 + L15)*136 + rb] = vh;
        }
    }
    __syncthreads();

    // coalesced stores to workspace
    {
        int row = t >> 1, sel = t & 1;
        const float4* s4 = (const float4*)&sm.qk[row*72 + sel*32];
        float4* d4 = (float4*)((sel ? Kg : Qs) + ((size_t)bg*1024 + qt*128 + row)*32);
        d4[0]=s4[0]; d4[1]=s4[1]; d4[2]=s4[2]; d4[3]=s4[3];
    }
    if (t < 128) {
        const float4* s4 = (const float4*)&sm.vrow[t*32];
        float4* d4 = (float4*)(Vg + ((size_t)bg*1024 + qt*128 + t)*32);
        d4[0]=s4[0]; d4[1]=s4[1]; d4[2]=s4[2]; d4[3]=s4[3];
    }
    {
        int e = t >> 3, c = t & 7;
        const float4* s4 = (const float4*)&sm.vt[e*136 + c*16];
        float4* d4 = (float4*)(Vtg + ((size_t)bg*32 + e)*1024 + qt*128 + c*16);
        d4[0]=s4[0]; d4[1]=s4[1];
    }
}

// ====================== Kernel A: attention + MLP ==========================
// 1024 blocks = bg(64) x qtile(16 of 64 rows), 256 threads (4 waves).
// wave w: qg = w>>1 (32 q rows), h = w&1 (k-halves: tiles h*8..h*8+7, TK=64).
// 16 waves/CU (4/SIMD). K/V tiles DMA-staged, double buffered, Vt XOR-swizzled
// via pre-swizzled per-lane global source addresses (LDS dest linear).
__global__ __launch_bounds__(256, 4) void attn_kernel(
    const _Float16* __restrict__ Qs, const _Float16* __restrict__ Kg,
    const _Float16* __restrict__ Vg, const _Float16* __restrict__ Vtg,
    const float* __restrict__ w_h1,  const float* __restrict__ b_h1,
    const float* __restrict__ w_h10, const float* __restrict__ b_h10,
    const float* __restrict__ w_h11, const float* __restrict__ b_h11,
    float* __restrict__ out)
{
    __shared__ struct __align__(16) {
        _Float16 Kt[2][2][64*32];   // [buf][h][kpos][e]        8KB*2
        _Float16 Vt[2][2][32*64];   // [buf][h][e][kpos] swz    8KB*2
        _Float16 xs[64*40];         // attn result [row][e]+pad 5KB
        float    linv[64];
    } sm;
    int t = threadIdx.x;
    int bid = blockIdx.x;
    int map = (bid & 7)*128 + (bid >> 3);       // XCD-contiguous work chunks
    int bg = map >> 4, qt = map & 15;
    int b = bg >> 1, g = bg & 1;
    int lane = t & 63, w = t >> 6;
    int L15 = lane & 15, quad = lane >> 4;
    int qg = w >> 1, h = w & 1;
    int qbase = qt*64;
    int lr = qg*32;
    int l7s = (L15 & 7) << 3;

    // Q B-frags straight from global (bias+scale folded by kernel P)
    const _Float16* qrow = Qs + ((size_t)bg*1024 + qbase + lr)*32;
    half8 bq0 = *(const half8*)(qrow + (size_t)L15*32 + quad*8);
    half8 bq1 = *(const half8*)(qrow + (size_t)(16 + L15)*32 + quad*8);

    // staging pointers (per-lane global, uniform LDS)
    const _Float16* kg0 = Kg + (size_t)bg*32768 + lane*8;
    int er = lane >> 3;
    int vswz = ((lane & 7)*8) ^ (er << 3);      // swizzled source column (halves)
    const _Float16* vg0 = Vtg + (size_t)bg*32768 + (size_t)er*1024 + vswz;

    auto stage = [&](int tile, int buf) {
        _Float16* kl = &sm.Kt[buf][h][0];
        _Float16* vl = &sm.Vt[buf][h][0];
        const _Float16* kgt = kg0 + (size_t)tile*2048;
        const _Float16* vgt = vg0 + (size_t)tile*64;
        #pragma unroll
        for (int c = 0; c < 2; c++) {
            int cc = qg*2 + c;                  // the 2 waves of this half split chunks
            gload16(kgt + cc*512,          kl + cc*512);
            gload16(vgt + (size_t)cc*8192, vl + cc*512);
        }
    };

    const floatx4 zz = {0.f,0.f,0.f,0.f};
    floatx4 o00 = zz, o01 = zz, o10 = zz, o11 = zz;
    float lsum0 = 0.f, lsum1 = 0.f;

    int buf = 0;
    stage(h*8, 0);
    __syncthreads();

    for (int i = 0; i < 8; i++) {
        if (i < 7) stage(h*8 + i + 1, buf ^ 1);
        const _Float16* Kl = &sm.Kt[buf][h][0];
        const _Float16* Vl = &sm.Vt[buf][h][0];
        __builtin_amdgcn_s_setprio(1);
        #pragma unroll
        for (int m8 = 0; m8 < 4; m8++) {
            half8 ak = *(const half8*)&Kl[(m8*16 + L15)*32 + quad*8];
            floatx4 s0 = MFMA32(ak, bq0, zz, 0,0,0);
            floatx4 s1 = MFMA32(ak, bq1, zz, 0,0,0);
            float p00 = EXP2(s0.x), p01 = EXP2(s0.y), p02 = EXP2(s0.z), p03 = EXP2(s0.w);
            float p10 = EXP2(s1.x), p11 = EXP2(s1.y), p12 = EXP2(s1.z), p13 = EXP2(s1.w);
            lsum0 += (p00+p01)+(p02+p03);
            lsum1 += (p10+p11)+(p12+p13);
            half2 pa = pkcvt(p00, p01);
            half2 pb = pkcvt(p02, p03);
            half2 pc = pkcvt(p10, p11);
            half2 pd = pkcvt(p12, p13);
            half4 a0 = { pa[0], pa[1], pb[0], pb[1] };
            half4 a1 = { pc[0], pc[1], pd[0], pd[1] };
            int vi = (m8*16 + quad*4) ^ l7s;
            half4 bv0 = *(const half4*)&Vl[L15*64 + vi];
            half4 bv1 = *(const half4*)&Vl[(16 + L15)*64 + vi];
            o00 = MFMA16(a0, bv0, o00, 0,0,0);
            o01 = MFMA16(a0, bv1, o01, 0,0,0);
            o10 = MFMA16(a1, bv0, o10, 0,0,0);
            o11 = MFMA16(a1, bv1, o11, 0,0,0);
        }
        __builtin_amdgcn_s_setprio(0);
        __syncthreads();
        buf ^= 1;
    }

    // fold quads -> every lane holds its q-row's partial denominator
    lsum0 += __shfl_xor(lsum0, 16, 64); lsum0 += __shfl_xor(lsum0, 32, 64);
    lsum1 += __shfl_xor(lsum1, 16, 64); lsum1 += __shfl_xor(lsum1, 32, 64);

    // combine k-split partials (tile buffers are dead: alias them)
    float* obuf  = (float*)&sm.Kt[0][0][0];     // 2 pairs x 64 lanes x 16 f32 = 8KB
    float* lpart = (float*)&sm.Vt[0][0][0];     // 64 f32
    if (h == 1) {
        float4* ob = (float4*)&obuf[((size_t)qg*64 + lane)*16];
        ob[0] = (float4){o00[0],o00[1],o00[2],o00[3]};
        ob[1] = (float4){o01[0],o01[1],o01[2],o01[3]};
        ob[2] = (float4){o10[0],o10[1],o10[2],o10[3]};
        ob[3] = (float4){o11[0],o11[1],o11[2],o11[3]};
        if (quad == 0) { lpart[qg*32 + L15] = lsum0; lpart[qg*32 + 16 + L15] = lsum1; }
    }
    __syncthreads();
    if (h == 0) {
        const float4* ob = (const float4*)&obuf[((size_t)qg*64 + lane)*16];
        float4 t0 = ob[0], t1 = ob[1], t2 = ob[2], t3 = ob[3];
        o00[0]+=t0.x; o00[1]+=t0.y; o00[2]+=t0.z; o00[3]+=t0.w;
        o01[0]+=t1.x; o01[1]+=t1.y; o01[2]+=t1.z; o01[3]+=t1.w;
        o10[0]+=t2.x; o10[1]+=t2.y; o10[2]+=t2.z; o10[3]+=t2.w;
        o11[0]+=t3.x; o11[1]+=t3.y; o11[2]+=t3.z; o11[3]+=t3.w;
        float li0 = 1.0f/(lsum0 + lpart[qg*32 + L15]);
        float li1 = 1.0f/(lsum1 + lpart[qg*32 + 16 + L15]);
        if (quad == 0) { sm.linv[qg*32 + L15] = li0; sm.linv[qg*32 + 16 + L15] = li1; }
    }
    __syncthreads();
    if (h == 0) {
        const floatx4* ofr[2][2] = { {&o00,&o01}, {&o10,&o11} };
        #pragma unroll
        for (int nt = 0; nt < 2; nt++) {
            float4 li = *(const float4*)&sm.linv[qg*32 + nt*16 + quad*4];
            #pragma unroll
            for (int et = 0; et < 2; et++) {
                floatx4 ov = *ofr[nt][et];
                sm.xs[(qg*32+nt*16+quad*4+0)*40 + et*16 + L15] = (_Float16)(ov[0]*li.x);
                sm.xs[(qg*32+nt*16+quad*4+1)*40 + et*16 + L15] = (_Float16)(ov[1]*li.y);
                sm.xs[(qg*32+nt*16+quad*4+2)*40 + et*16 + L15] = (_Float16)(ov[2]*li.z);
                sm.xs[(qg*32+nt*16+quad*4+3)*40 + et*16 + L15] = (_Float16)(ov[3]*li.w);
            }
        }
    }
    __syncthreads();

    // ---- MLP: wave handles 16 rows (lrh..lrh+15), all 32 outs of its group ----
    int lrh = qg*32 + h*16;
    half4 a1f[2][4], a2f[2][2], a3f[2][2];
    #pragma unroll
    for (int mt = 0; mt < 2; mt++) {
        #pragma unroll
        for (int kt = 0; kt < 4; kt++) {
            float4 f = *(const float4*)(w_h1 + (size_t)(g*32+mt*16+L15)*64 + kt*16 + quad*4);
            half2 ha = pkcvt(f.x, f.y);
            half2 hb = pkcvt(f.z, f.w);
            half4 hh = { ha[0], ha[1], hb[0], hb[1] };
            a1f[mt][kt] = hh;
        }
        #pragma unroll
        for (int kt = 0; kt < 2; kt++) {
            float4 f = *(const float4*)(w_h10 + (size_t)(g*32+mt*16+L15)*32 + kt*16 + quad*4);
            half2 ha = pkcvt(f.x, f.y);
            half2 hb = pkcvt(f.z, f.w);
            half4 hh = { ha[0], ha[1], hb[0], hb[1] };
            a2f[mt][kt] = hh;
            float4 f2 = *(const float4*)(w_h11 + (size_t)(g*32+mt*16+L15)*32 + kt*16 + quad*4);
            half2 hc = pkcvt(f2.x, f2.y);
            half2 hd = pkcvt(f2.z, f2.w);
            half4 h2 = { hc[0], hc[1], hd[0], hd[1] };
            a3f[mt][kt] = h2;
        }
    }

    floatx4 d1[2];
    #pragma unroll
    for (int mt = 0; mt < 2; mt++) {
        float4 bb = *(const float4*)(b_h1 + g*32 + mt*16 + quad*4);
        d1[mt] = (floatx4){bb.x, bb.y, bb.z, bb.w};
    }
    size_t grow = (size_t)bg*1024 + qbase + lrh + L15;
    #pragma unroll
    for (int kt = 0; kt < 4; kt++) {
        half4 b1;
        if (kt < 2) b1 = *(const half4*)(Vg + grow*32 + kt*16 + quad*4);
        else        b1 = *(const half4*)&sm.xs[(lrh + L15)*40 + (kt-2)*16 + quad*4];
        d1[0] = MFMA16(a1f[0][kt], b1, d1[0], 0,0,0);
        d1[1] = MFMA16(a1f[1][kt], b1, d1[1], 0,0,0);
    }
    half4 h1b[2];
    #pragma unroll
    for (int mt = 0; mt < 2; mt++) {
        float v0 = d1[mt][0]; v0 = (v0>=0.f)?v0:NEG*v0;
        float v1 = d1[mt][1]; v1 = (v1>=0.f)?v1:NEG*v1;
        float v2 = d1[mt][2]; v2 = (v2>=0.f)?v2:NEG*v2;
        float v3 = d1[mt][3]; v3 = (v3>=0.f)?v3:NEG*v3;
        half2 ha = pkcvt(v0, v1);
        half2 hb = pkcvt(v2, v3);
        half4 hh = { ha[0], ha[1], hb[0], hb[1] };
        h1b[mt] = hh;
    }
    floatx4 d2[2];
    #pragma unroll
    for (int mt = 0; mt < 2; mt++) {
        float4 bb = *(const float4*)(b_h10 + g*32 + mt*16 + quad*4);
        d2[mt] = (floatx4){bb.x, bb.y, bb.z, bb.w};
        #pragma unroll
        for (int kt = 0; kt < 2; kt++)
            d2[mt] = MFMA16(a2f[mt][kt], h1b[kt], d2[mt], 0,0,0);
    }
    half4 h2b[2];
    #pragma unroll
    for (int mt = 0; mt < 2; mt++) {
        float v0 = d2[mt][0]; v0 = (v0>=0.f)?v0:NEG*v0;
        float v1 = d2[mt][1]; v1 = (v1>=0.f)?v1:NEG*v1;
        float v2 = d2[mt][2]; v2 = (v2>=0.f)?v2:NEG*v2;
        float v3 = d2[mt][3]; v3 = (v3>=0.f)?v3:NEG*v3;
        half2 ha = pkcvt(v0, v1);
        half2 hb = pkcvt(v2, v3);
        half4 hh = { ha[0], ha[1], hb[0], hb[1] };
        h2b[mt] = hh;
    }
    floatx4 d3[2];
    #pragma unroll
    for (int mt = 0; mt < 2; mt++) {
        float4 bb = *(const float4*)(b_h11 + g*32 + mt*16 + quad*4);
        d3[mt] = (floatx4){bb.x, bb.y, bb.z, bb.w};
        #pragma unroll
        for (int kt = 0; kt < 2; kt++)
            d3[mt] = MFMA16(a3f[mt][kt], h2b[kt], d3[mt], 0,0,0);
    }
    #pragma unroll
    for (int mt = 0; mt < 2; mt++) {
        float4 ov;
        ov.x = d3[mt][0]; ov.x = (ov.x>=0.f)?ov.x:NEG*ov.x;
        ov.y = d3[mt][1]; ov.y = (ov.y>=0.f)?ov.y:NEG*ov.y;
        ov.z = d3[mt][2]; ov.z = (ov.z>=0.f)?ov.z:NEG*ov.z;
        ov.w = d3[mt][3]; ov.w = (ov.w>=0.f)?ov.w:NEG*ov.w;
        *(float4*)(out + ((size_t)b*N_ + qbase + lrh + L15)*64 + g*32 + mt*16 + quad*4) = ov;
    }
}

extern "C" void kernel_launch(void* const* d_in, const int* in_sizes, int n_in,
                              void* d_out, int out_size, void* d_ws, size_t ws_size,
                              hipStream_t stream) {
    const float* x_e   = (const float*)d_in[0];
    const float* w_qkv = (const float*)d_in[1];
    const float* b_qkv = (const float*)d_in[2];
    const float* w_h1  = (const float*)d_in[3];
    const float* b_h1  = (const float*)d_in[4];
    const float* w_h10 = (const float*)d_in[5];
    const float* b_h10 = (const float*)d_in[6];
    const float* w_h11 = (const float*)d_in[7];
    const float* b_h11 = (const float*)d_in[8];
    float* out = (float*)d_out;

    _Float16* base = (_Float16*)d_ws;
    _Float16* Qs  = base;                 // 64*1024*32 halves = 4MB
    _Float16* Kg  = base + (1u<<21);      // 4MB
    _Float16* Vg  = base + (2u<<21);      // 4MB
    _Float16* Vtg = base + (3u<<21);      // 4MB

    hipLaunchKernelGGL(proj_kernel, dim3(512), dim3(256), 0, stream,
                       x_e, w_qkv, b_qkv, Qs, Kg, Vg, Vtg);
    hipLaunchKernelGGL(attn_kernel, dim3(1024), dim3(256), 0, stream,
                       Qs, Kg, Vg, Vtg, w_h1, b_h1, w_h10, b_h10, w_h11, b_h11, out);
}